// Round 1
// baseline (143.137 us; speedup 1.0000x reference)
//
#include <hip/hip_runtime.h>
#include <hip/hip_bf16.h>

// Problem constants
#define D_IN 1024
#define D_EMB 512
#define HIDDEN 256
#define NUM_CLASSES 64
#define N_SUPPORT 4096
#define N_QUERY 8192

typedef __bf16 bf16x8 __attribute__((ext_vector_type(8)));
typedef __bf16 bf16x4 __attribute__((ext_vector_type(4)));
typedef float f32x4 __attribute__((ext_vector_type(4)));

#define GLOAD_LDS16(g, l)                                                          \
  __builtin_amdgcn_global_load_lds(                                                \
      (const __attribute__((address_space(1))) unsigned int*)(g),                  \
      (__attribute__((address_space(3))) unsigned int*)(l), 16, 0, 0)

// ---------------------------------------------------------------------------
// fp32 -> bf16 convert (vectorized: float4 in, 4x bf16 out)
// ---------------------------------------------------------------------------
__global__ void convert_f32_bf16(const float* __restrict__ in,
                                 __bf16* __restrict__ out, long n) {
  long i = ((long)blockIdx.x * blockDim.x + threadIdx.x) * 4;
  if (i >= n) return;
  float4 v = *(const float4*)(in + i);
  bf16x4 o;
  o[0] = (__bf16)v.x; o[1] = (__bf16)v.y; o[2] = (__bf16)v.z; o[3] = (__bf16)v.w;
  *(bf16x4*)(out + i) = o;
}

// ---------------------------------------------------------------------------
// LDS-tiled transpose: in [rows][cols] f32  ->  out [cols][rows] bf16
// block (32,8), grid (cols/32, rows/32). rows,cols multiples of 32.
// ---------------------------------------------------------------------------
__global__ void transpose_f32_to_bf16(const float* __restrict__ in,
                                      __bf16* __restrict__ out,
                                      int rows, int cols) {
  __shared__ float tile[32][33];
  int bx = blockIdx.x * 32;  // col base
  int by = blockIdx.y * 32;  // row base
  int tx = threadIdx.x;      // 0..31
  int ty = threadIdx.y;      // 0..7
#pragma unroll
  for (int i = ty; i < 32; i += 8)
    tile[i][tx] = in[(long)(by + i) * cols + bx + tx];
  __syncthreads();
#pragma unroll
  for (int i = ty; i < 32; i += 8)
    out[(long)(bx + i) * rows + by + tx] = (__bf16)tile[tx][i];
}

// ---------------------------------------------------------------------------
// bf16 MFMA GEMM:  C[M][N] = A[M][K] @ BT[N][K]^T   (both row-major bf16)
// BM=128, BN template (128 or 64), BK=32. 4 waves in 2x2, 64 x (BN/2) per wave.
// EPI 0: C = bf16, relu(acc + bias[col]); EPI 1: C = f32, plain acc.
// ---------------------------------------------------------------------------
template <int BN, int EPI>
__global__ __launch_bounds__(256, 2) void gemm_bt(
    const __bf16* __restrict__ A, const __bf16* __restrict__ BT,
    const float* __restrict__ bias, void* __restrict__ C,
    int M, int N, int K) {
  constexpr int BM = 128;
  constexpr int BK = 32;
  constexpr int WN = BN / 2;   // wave tile cols
  constexpr int NR = WN / 16;  // n-fragments per wave
  constexpr int MR = 4;        // 64 rows per wave

  __shared__ __align__(16) __bf16 As[BM * BK];
  __shared__ __align__(16) __bf16 Bs[BN * BK];

  const int tid = threadIdx.x;
  const int wave = tid >> 6;
  const int lane = tid & 63;
  const int m0 = blockIdx.x * BM;
  const int n0 = blockIdx.y * BN;
  const int wr = wave >> 1;  // 0..1
  const int wc = wave & 1;   // 0..1
  const int l16 = lane & 15;
  const int half = lane >> 4;  // 0..3

  f32x4 acc[MR][NR];
#pragma unroll
  for (int m = 0; m < MR; ++m)
#pragma unroll
    for (int n = 0; n < NR; ++n) acc[m][n] = (f32x4)0.0f;

  for (int k0 = 0; k0 < K; k0 += BK) {
    // stage A tile: BM*BK bf16 = BM/64 calls of 256 lanes x 16B
#pragma unroll
    for (int q = 0; q < BM / 64; ++q) {
      int chunk = q * 256 + tid;        // 16B chunk index
      int row = chunk >> 2;             // BK=32 -> 4 chunks per row
      int kc = chunk & 3;
      GLOAD_LDS16(A + (long)(m0 + row) * K + k0 + kc * 8, As + chunk * 8);
    }
#pragma unroll
    for (int q = 0; q < BN / 64; ++q) {
      int chunk = q * 256 + tid;
      int row = chunk >> 2;
      int kc = chunk & 3;
      GLOAD_LDS16(BT + (long)(n0 + row) * K + k0 + kc * 8, Bs + chunk * 8);
    }
    asm volatile("s_waitcnt vmcnt(0)" ::: "memory");
    __syncthreads();

    bf16x8 a[MR], b[NR];
#pragma unroll
    for (int m = 0; m < MR; ++m)
      a[m] = *(const bf16x8*)(As + (wr * 64 + m * 16 + l16) * BK + half * 8);
#pragma unroll
    for (int n = 0; n < NR; ++n)
      b[n] = *(const bf16x8*)(Bs + (wc * WN + n * 16 + l16) * BK + half * 8);
#pragma unroll
    for (int m = 0; m < MR; ++m)
#pragma unroll
      for (int n = 0; n < NR; ++n)
        acc[m][n] = __builtin_amdgcn_mfma_f32_16x16x32_bf16(a[m], b[n],
                                                            acc[m][n], 0, 0, 0);
    __syncthreads();
  }

  // epilogue: C/D layout col = lane&15, row = (lane>>4)*4 + j  [m89/m91]
#pragma unroll
  for (int m = 0; m < MR; ++m) {
#pragma unroll
    for (int n = 0; n < NR; ++n) {
#pragma unroll
      for (int j = 0; j < 4; ++j) {
        int row = m0 + wr * 64 + m * 16 + half * 4 + j;
        int col = n0 + wc * WN + n * 16 + l16;
        float v = acc[m][n][j];
        if (EPI == 0) {
          v += bias[col];
          v = fmaxf(v, 0.0f);
          ((__bf16*)C)[(long)row * N + col] = (__bf16)v;
        } else {
          ((float*)C)[(long)row * N + col] = v;
        }
      }
    }
  }
}

// ---------------------------------------------------------------------------
// class index build: per-class row lists via atomics (cnt pre-zeroed)
// ---------------------------------------------------------------------------
__global__ void build_index(const int* __restrict__ labels, int* __restrict__ cnt,
                            int* __restrict__ idx) {
  int i = blockIdx.x * 256 + threadIdx.x;  // 4096 threads total
  int lab = labels[i];
  int pos = atomicAdd(&cnt[lab], 1);
  if (pos < 512) idx[lab * 512 + pos] = i;
}

// ---------------------------------------------------------------------------
// per-class: mean of s_emb rows (fp32 accum over bf16), then
// cpb[c][n] = means[c] . Wc[:,n] + b1[n]   (fp32, Wc = W1[512:])
// one block (256 threads) per class.
// ---------------------------------------------------------------------------
__global__ __launch_bounds__(256) void class_kernel(
    const __bf16* __restrict__ s_emb, const int* __restrict__ cnt,
    const int* __restrict__ idx, const float* __restrict__ W1,
    const float* __restrict__ b1, float* __restrict__ cpb) {
  __shared__ float mean_s[D_EMB];
  int c = blockIdx.x;
  int tid = threadIdx.x;
  int nc = cnt[c];
  if (nc > 512) nc = 512;
  float a0 = 0.0f, a1 = 0.0f;
  for (int j = 0; j < nc; ++j) {
    int row = idx[c * 512 + j];
    const __bf16* r = s_emb + (long)row * D_EMB;
    a0 += (float)r[tid];
    a1 += (float)r[tid + 256];
  }
  float inv = 1.0f / fmaxf((float)nc, 1.0f);
  mean_s[tid] = a0 * inv;
  mean_s[tid + 256] = a1 * inv;
  __syncthreads();

  float acc = b1[tid];  // n = tid, 0..255
#pragma unroll 8
  for (int k = 0; k < D_EMB; ++k)
    acc = fmaf(mean_s[k], W1[(long)(D_EMB + k) * HIDDEN + tid], acc);
  cpb[c * HIDDEN + tid] = acc;
}

// ---------------------------------------------------------------------------
// fused score: out[q][c] = sigmoid( sum_k relu(qp[q,k]+cpb[c,k]) * W2[k] + b2 )
// block = 256 threads = 4 q-rows x 64 classes; cpb in LDS with +1 pad.
// ---------------------------------------------------------------------------
__global__ __launch_bounds__(256) void score_kernel(
    const float* __restrict__ qp, const float* __restrict__ cpb,
    const float* __restrict__ W2, const float* __restrict__ b2,
    float* __restrict__ out) {
  __shared__ float cpb_s[NUM_CLASSES * (HIDDEN + 1)];
  __shared__ float qp_s[4 * HIDDEN];
  __shared__ float w2_s[HIDDEN];
  int tid = threadIdx.x;
  int q0 = blockIdx.x * 4;

  w2_s[tid] = W2[tid];
  for (int i = tid; i < 4 * HIDDEN; i += 256) qp_s[i] = qp[(long)q0 * HIDDEN + i];
  for (int i = tid; i < NUM_CLASSES * HIDDEN; i += 256)
    cpb_s[(i >> 8) * (HIDDEN + 1) + (i & (HIDDEN - 1))] = cpb[i];
  __syncthreads();

  int qi = tid >> 6;  // wave id -> qp row is wave-uniform (LDS broadcast)
  int c = tid & 63;
  const float* qrow = qp_s + qi * HIDDEN;
  const float* crow = cpb_s + c * (HIDDEN + 1);
  float acc = 0.0f;
#pragma unroll 8
  for (int k = 0; k < HIDDEN; ++k)
    acc = fmaf(fmaxf(qrow[k] + crow[k], 0.0f), w2_s[k], acc);
  float x = acc + b2[0];
  out[(long)(q0 + qi) * NUM_CLASSES + c] = 1.0f / (1.0f + __expf(-x));
}

// ---------------------------------------------------------------------------
extern "C" void kernel_launch(void* const* d_in, const int* in_sizes, int n_in,
                              void* d_out, int out_size, void* d_ws,
                              size_t ws_size, hipStream_t stream) {
  const float* support = (const float*)d_in[0];
  const float* query   = (const float*)d_in[1];
  const int*   labels  = (const int*)d_in[2];
  const float* W_e     = (const float*)d_in[3];
  const float* b_e     = (const float*)d_in[4];
  const float* W1      = (const float*)d_in[5];
  const float* b1      = (const float*)d_in[6];
  const float* W2      = (const float*)d_in[7];
  const float* b2      = (const float*)d_in[8];
  float* out = (float*)d_out;

  char* ws = (char*)d_ws;
  size_t off = 0;
  auto alloc = [&](size_t bytes) {
    void* p = ws + off;
    off = (off + bytes + 255) & ~(size_t)255;
    return p;
  };
  const long NTOT = N_SUPPORT + N_QUERY;  // 12288
  __bf16* Xbf = (__bf16*)alloc((size_t)NTOT * D_IN * 2);          // 25.2 MB
  __bf16* WeT = (__bf16*)alloc((size_t)D_EMB * D_IN * 2);         // 1 MB
  __bf16* WqT = (__bf16*)alloc((size_t)HIDDEN * D_EMB * 2);       // 256 KB
  __bf16* emb = (__bf16*)alloc((size_t)NTOT * D_EMB * 2);         // 12.6 MB
  float*  qp  = (float*)alloc((size_t)N_QUERY * HIDDEN * 4);      // 8.4 MB
  float*  cpb = (float*)alloc((size_t)NUM_CLASSES * HIDDEN * 4);  // 64 KB
  int*    cnt = (int*)alloc(NUM_CLASSES * 4);
  int*    idx = (int*)alloc((size_t)NUM_CLASSES * 512 * 4);       // 128 KB

  hipMemsetAsync(cnt, 0, NUM_CLASSES * 4, stream);

  // fp32 -> bf16 input conversion ([support; query] concatenated)
  convert_f32_bf16<<<(N_SUPPORT * D_IN) / 1024, 256, 0, stream>>>(
      support, Xbf, (long)N_SUPPORT * D_IN);
  convert_f32_bf16<<<(N_QUERY * D_IN) / 1024, 256, 0, stream>>>(
      query, Xbf + (long)N_SUPPORT * D_IN, (long)N_QUERY * D_IN);

  // W_e [1024][512] -> WeT [512][1024] bf16 ; Wq = W1[:512] [512][256] -> WqT [256][512]
  transpose_f32_to_bf16<<<dim3(D_EMB / 32, D_IN / 32), dim3(32, 8), 0, stream>>>(
      W_e, WeT, D_IN, D_EMB);
  transpose_f32_to_bf16<<<dim3(HIDDEN / 32, D_EMB / 32), dim3(32, 8), 0, stream>>>(
      W1, WqT, D_EMB, HIDDEN);

  // embeddings: relu(X @ W_e + b_e) -> bf16 [12288][512]
  gemm_bt<128, 0><<<dim3(NTOT / 128, D_EMB / 128), 256, 0, stream>>>(
      Xbf, WeT, b_e, emb, NTOT, D_EMB, D_IN);

  // class prototypes -> cpb (includes b1)
  build_index<<<N_SUPPORT / 256, 256, 0, stream>>>(labels, cnt, idx);
  class_kernel<<<NUM_CLASSES, 256, 0, stream>>>(emb, cnt, idx, W1, b1, cpb);

  // qp = q_emb @ Wq  (f32 out [8192][256])
  gemm_bt<64, 1><<<dim3(N_QUERY / 128, HIDDEN / 64), 256, 0, stream>>>(
      emb + (long)N_SUPPORT * D_EMB, WqT, nullptr, qp, N_QUERY, HIDDEN, D_EMB);

  // fused relation score
  score_kernel<<<N_QUERY / 4, 256, 0, stream>>>(qp, cpb, W2, b2, out);
}

// Round 2
// 115.160 us; speedup vs baseline: 1.2429x; 1.2429x over previous
//
#include <hip/hip_runtime.h>
#include <hip/hip_bf16.h>

// Problem constants
#define D_IN 1024
#define D_EMB 512
#define HIDDEN 256
#define NUM_CLASSES 64
#define N_SUPPORT 4096
#define N_QUERY 8192

typedef __bf16 bf16x8 __attribute__((ext_vector_type(8)));
typedef __bf16 bf16x4 __attribute__((ext_vector_type(4)));
typedef float f32x4 __attribute__((ext_vector_type(4)));

#define GLOAD_LDS16(g, l)                                                          \
  __builtin_amdgcn_global_load_lds(                                                \
      (const __attribute__((address_space(1))) unsigned int*)(g),                  \
      (__attribute__((address_space(3))) unsigned int*)(l), 16, 0, 0)

// ---------------------------------------------------------------------------
// fp32 -> bf16 convert of [support ; query] into one bf16 buffer (fused)
// ---------------------------------------------------------------------------
__global__ void convert_f32_bf16(const float* __restrict__ support,
                                 const float* __restrict__ query,
                                 __bf16* __restrict__ out) {
  const long nsup = (long)N_SUPPORT * D_IN;
  long i = ((long)blockIdx.x * blockDim.x + threadIdx.x) * 4;
  const float* src = (i < nsup) ? (support + i) : (query + (i - nsup));
  float4 v = *(const float4*)src;
  bf16x4 o;
  o[0] = (__bf16)v.x; o[1] = (__bf16)v.y; o[2] = (__bf16)v.z; o[3] = (__bf16)v.w;
  *(bf16x4*)(out + i) = o;
}

// ---------------------------------------------------------------------------
// LDS-tiled transpose: in [rows][cols] f32  ->  out [cols][rows] bf16
// block (32,8), grid (cols/32, rows/32). rows,cols multiples of 32.
// ---------------------------------------------------------------------------
__global__ void transpose_f32_to_bf16(const float* __restrict__ in,
                                      __bf16* __restrict__ out,
                                      int rows, int cols) {
  __shared__ float tile[32][33];
  int bx = blockIdx.x * 32;  // col base
  int by = blockIdx.y * 32;  // row base
  int tx = threadIdx.x;      // 0..31
  int ty = threadIdx.y;      // 0..7
#pragma unroll
  for (int i = ty; i < 32; i += 8)
    tile[i][tx] = in[(long)(by + i) * cols + bx + tx];
  __syncthreads();
#pragma unroll
  for (int i = ty; i < 32; i += 8)
    out[(long)(bx + i) * rows + by + tx] = (__bf16)tile[tx][i];
}

// ---------------------------------------------------------------------------
// bf16 MFMA GEMM:  C[M][N] = A[M][K] @ BT[N][K]^T   (both row-major bf16)
// BM=128, BN template (128 or 64), BK=32. 4 waves in 2x2, 64 x (BN/2) per wave.
// EPI 0: C = bf16, relu(acc + bias[col]); EPI 1: C = f32, acc + bias[col].
// ---------------------------------------------------------------------------
template <int BN, int EPI>
__global__ __launch_bounds__(256, 2) void gemm_bt(
    const __bf16* __restrict__ A, const __bf16* __restrict__ BT,
    const float* __restrict__ bias, void* __restrict__ C,
    int M, int N, int K) {
  constexpr int BM = 128;
  constexpr int BK = 32;
  constexpr int WN = BN / 2;   // wave tile cols
  constexpr int NR = WN / 16;  // n-fragments per wave
  constexpr int MR = 4;        // 64 rows per wave

  __shared__ __align__(16) __bf16 As[BM * BK];
  __shared__ __align__(16) __bf16 Bs[BN * BK];

  const int tid = threadIdx.x;
  const int wave = tid >> 6;
  const int lane = tid & 63;
  const int m0 = blockIdx.x * BM;
  const int n0 = blockIdx.y * BN;
  const int wr = wave >> 1;  // 0..1
  const int wc = wave & 1;   // 0..1
  const int l16 = lane & 15;
  const int half = lane >> 4;  // 0..3

  f32x4 acc[MR][NR];
#pragma unroll
  for (int m = 0; m < MR; ++m)
#pragma unroll
    for (int n = 0; n < NR; ++n) acc[m][n] = (f32x4)0.0f;

  for (int k0 = 0; k0 < K; k0 += BK) {
#pragma unroll
    for (int q = 0; q < BM / 64; ++q) {
      int chunk = q * 256 + tid;        // 16B chunk index
      int row = chunk >> 2;             // BK=32 -> 4 chunks per row
      int kc = chunk & 3;
      GLOAD_LDS16(A + (long)(m0 + row) * K + k0 + kc * 8, As + chunk * 8);
    }
#pragma unroll
    for (int q = 0; q < BN / 64; ++q) {
      int chunk = q * 256 + tid;
      int row = chunk >> 2;
      int kc = chunk & 3;
      GLOAD_LDS16(BT + (long)(n0 + row) * K + k0 + kc * 8, Bs + chunk * 8);
    }
    asm volatile("s_waitcnt vmcnt(0)" ::: "memory");
    __syncthreads();

    bf16x8 a[MR], b[NR];
#pragma unroll
    for (int m = 0; m < MR; ++m)
      a[m] = *(const bf16x8*)(As + (wr * 64 + m * 16 + l16) * BK + half * 8);
#pragma unroll
    for (int n = 0; n < NR; ++n)
      b[n] = *(const bf16x8*)(Bs + (wc * WN + n * 16 + l16) * BK + half * 8);
#pragma unroll
    for (int m = 0; m < MR; ++m)
#pragma unroll
      for (int n = 0; n < NR; ++n)
        acc[m][n] = __builtin_amdgcn_mfma_f32_16x16x32_bf16(a[m], b[n],
                                                            acc[m][n], 0, 0, 0);
    __syncthreads();
  }

  // epilogue: C/D layout col = lane&15, row = (lane>>4)*4 + j  [m89/m91]
#pragma unroll
  for (int m = 0; m < MR; ++m) {
#pragma unroll
    for (int n = 0; n < NR; ++n) {
#pragma unroll
      for (int j = 0; j < 4; ++j) {
        int row = m0 + wr * 64 + m * 16 + half * 4 + j;
        int col = n0 + wc * WN + n * 16 + l16;
        float v = acc[m][n][j] + bias[col];
        if (EPI == 0) {
          v = fmaxf(v, 0.0f);
          ((__bf16*)C)[(long)row * N + col] = (__bf16)v;
        } else {
          ((float*)C)[(long)row * N + col] = v;
        }
      }
    }
  }
}

// ---------------------------------------------------------------------------
// class index build: per-class row lists via atomics (cnt pre-zeroed)
// ---------------------------------------------------------------------------
__global__ void build_index(const int* __restrict__ labels, int* __restrict__ cnt,
                            int* __restrict__ idx) {
  int i = blockIdx.x * 256 + threadIdx.x;  // 4096 threads total
  int lab = labels[i];
  int pos = atomicAdd(&cnt[lab], 1);
  if (pos < 512) idx[lab * 512 + pos] = i;
}

// ---------------------------------------------------------------------------
// class sums, parallel: grid (64 classes, 8 slices). Block (c,s) accumulates
// rows idx[c][s], idx[c][s+8], ... in registers, then one atomicAdd per col.
// sums pre-zeroed. 8-way atomic contention only.
// ---------------------------------------------------------------------------
__global__ __launch_bounds__(256) void proto_partial(
    const __bf16* __restrict__ s_emb, const int* __restrict__ cnt,
    const int* __restrict__ idx, float* __restrict__ sums) {
  int c = blockIdx.x;
  int s = blockIdx.y;  // 0..7
  int tid = threadIdx.x;
  int nc = cnt[c];
  if (nc > 512) nc = 512;
  float a0 = 0.0f, a1 = 0.0f;
  for (int j = s; j < nc; j += 8) {
    int row = idx[c * 512 + j];
    const __bf16* r = s_emb + (long)row * D_EMB;
    a0 += (float)r[tid];
    a1 += (float)r[tid + 256];
  }
  atomicAdd(&sums[c * D_EMB + tid], a0);
  atomicAdd(&sums[c * D_EMB + tid + 256], a1);
}

// ---------------------------------------------------------------------------
// cpb[c][n] = sum_k (sums[c][k]/max(cnt[c],1)) * W1[(D_EMB+k)][n]
// grid (64 classes, 4 k-chunks of 128); cpb pre-zeroed; partials via atomicAdd.
// b1 is folded into the qp GEMM bias instead.
// ---------------------------------------------------------------------------
__global__ __launch_bounds__(256) void proto_cpb(
    const float* __restrict__ sums, const int* __restrict__ cnt,
    const float* __restrict__ W1, float* __restrict__ cpb) {
  __shared__ float ls[128];
  int c = blockIdx.x;
  int k0 = blockIdx.y * 128;
  int tid = threadIdx.x;
  float inv = 1.0f / fmaxf((float)min(cnt[c], 512), 1.0f);
  if (tid < 128) ls[tid] = sums[c * D_EMB + k0 + tid] * inv;
  __syncthreads();

  float acc = 0.0f;
#pragma unroll 8
  for (int k = 0; k < 128; ++k)
    acc = fmaf(ls[k], W1[(long)(D_EMB + k0 + k) * HIDDEN + tid], acc);
  atomicAdd(&cpb[c * HIDDEN + tid], acc);
}

// ---------------------------------------------------------------------------
// fused score: out[q][c] = sigmoid( sum_k relu(qp[q,k]+cpb[c,k]) * W2[k] + b2 )
// qp already includes b1. block = 256 threads = 4 q-rows x 64 classes.
// ---------------------------------------------------------------------------
__global__ __launch_bounds__(256) void score_kernel(
    const float* __restrict__ qp, const float* __restrict__ cpb,
    const float* __restrict__ W2, const float* __restrict__ b2,
    float* __restrict__ out) {
  __shared__ float cpb_s[NUM_CLASSES * (HIDDEN + 1)];
  __shared__ float qp_s[4 * HIDDEN];
  __shared__ float w2_s[HIDDEN];
  int tid = threadIdx.x;
  int q0 = blockIdx.x * 4;

  w2_s[tid] = W2[tid];
  for (int i = tid; i < 4 * HIDDEN; i += 256) qp_s[i] = qp[(long)q0 * HIDDEN + i];
  for (int i = tid; i < NUM_CLASSES * HIDDEN; i += 256)
    cpb_s[(i >> 8) * (HIDDEN + 1) + (i & (HIDDEN - 1))] = cpb[i];
  __syncthreads();

  int qi = tid >> 6;  // wave id -> qp row is wave-uniform (LDS broadcast)
  int c = tid & 63;
  const float* qrow = qp_s + qi * HIDDEN;
  const float* crow = cpb_s + c * (HIDDEN + 1);
  float acc = 0.0f;
#pragma unroll 8
  for (int k = 0; k < HIDDEN; ++k)
    acc = fmaf(fmaxf(qrow[k] + crow[k], 0.0f), w2_s[k], acc);
  float x = acc + b2[0];
  out[(long)(q0 + qi) * NUM_CLASSES + c] = 1.0f / (1.0f + __expf(-x));
}

// ---------------------------------------------------------------------------
extern "C" void kernel_launch(void* const* d_in, const int* in_sizes, int n_in,
                              void* d_out, int out_size, void* d_ws,
                              size_t ws_size, hipStream_t stream) {
  const float* support = (const float*)d_in[0];
  const float* query   = (const float*)d_in[1];
  const int*   labels  = (const int*)d_in[2];
  const float* W_e     = (const float*)d_in[3];
  const float* b_e     = (const float*)d_in[4];
  const float* W1      = (const float*)d_in[5];
  const float* b1      = (const float*)d_in[6];
  const float* W2      = (const float*)d_in[7];
  const float* b2      = (const float*)d_in[8];
  float* out = (float*)d_out;

  char* ws = (char*)d_ws;
  size_t off = 0;
  auto alloc = [&](size_t bytes) {
    void* p = ws + off;
    off = (off + bytes + 255) & ~(size_t)255;
    return p;
  };
  const long NTOT = N_SUPPORT + N_QUERY;  // 12288
  __bf16* Xbf = (__bf16*)alloc((size_t)NTOT * D_IN * 2);          // 25.2 MB
  __bf16* WeT = (__bf16*)alloc((size_t)D_EMB * D_IN * 2);         // 1 MB
  __bf16* WqT = (__bf16*)alloc((size_t)HIDDEN * D_EMB * 2);       // 256 KB
  __bf16* emb = (__bf16*)alloc((size_t)NTOT * D_EMB * 2);         // 12.6 MB
  float*  qp  = (float*)alloc((size_t)N_QUERY * HIDDEN * 4);      // 8.4 MB
  // zero-init region (one memset): sums | cpb | cnt
  float*  sums = (float*)alloc((size_t)NUM_CLASSES * D_EMB * 4);  // 128 KB
  float*  cpb  = (float*)alloc((size_t)NUM_CLASSES * HIDDEN * 4); // 64 KB
  int*    cnt  = (int*)alloc(NUM_CLASSES * 4);
  int*    idx  = (int*)alloc((size_t)NUM_CLASSES * 512 * 4);      // 128 KB

  hipMemsetAsync(sums, 0,
                 (size_t)NUM_CLASSES * D_EMB * 4 + 256 +          // sums (rounded)
                 (size_t)NUM_CLASSES * HIDDEN * 4 + 256,          // cpb + cnt pad
                 stream);

  // fp32 -> bf16 input conversion ([support; query] concatenated)
  convert_f32_bf16<<<(NTOT * D_IN) / 1024, 256, 0, stream>>>(support, query, Xbf);

  // W_e [1024][512] -> WeT [512][1024] bf16 ; Wq = W1[:512] [512][256] -> WqT [256][512]
  transpose_f32_to_bf16<<<dim3(D_EMB / 32, D_IN / 32), dim3(32, 8), 0, stream>>>(
      W_e, WeT, D_IN, D_EMB);
  transpose_f32_to_bf16<<<dim3(HIDDEN / 32, D_EMB / 32), dim3(32, 8), 0, stream>>>(
      W1, WqT, D_EMB, HIDDEN);

  // embeddings: relu(X @ W_e + b_e) -> bf16 [12288][512]
  gemm_bt<128, 0><<<dim3(NTOT / 128, D_EMB / 128), 256, 0, stream>>>(
      Xbf, WeT, b_e, emb, NTOT, D_EMB, D_IN);

  // class prototypes: index lists -> partial sums -> cpb projection
  build_index<<<N_SUPPORT / 256, 256, 0, stream>>>(labels, cnt, idx);
  proto_partial<<<dim3(NUM_CLASSES, 8), 256, 0, stream>>>(emb, cnt, idx, sums);
  proto_cpb<<<dim3(NUM_CLASSES, 4), 256, 0, stream>>>(sums, cnt, W1, cpb);

  // qp = q_emb @ Wq + b1  (f32 out [8192][256])
  gemm_bt<64, 1><<<dim3(N_QUERY / 128, HIDDEN / 64), 256, 0, stream>>>(
      emb + (long)N_SUPPORT * D_EMB, WqT, b1, qp, N_QUERY, HIDDEN, D_EMB);

  // fused relation score
  score_kernel<<<N_QUERY / 4, 256, 0, stream>>>(qp, cpb, W2, b2, out);
}

// Round 3
// 115.111 us; speedup vs baseline: 1.2435x; 1.0004x over previous
//
#include <hip/hip_runtime.h>
#include <hip/hip_bf16.h>

// Problem constants
#define D_IN 1024
#define D_EMB 512
#define HIDDEN 256
#define NUM_CLASSES 64
#define N_SUPPORT 4096
#define N_QUERY 8192

typedef __bf16 bf16x8 __attribute__((ext_vector_type(8)));
typedef __bf16 bf16x4 __attribute__((ext_vector_type(4)));
typedef float f32x4 __attribute__((ext_vector_type(4)));

#define GLOAD_LDS16(g, l)                                                          \
  __builtin_amdgcn_global_load_lds(                                                \
      (const __attribute__((address_space(1))) unsigned int*)(g),                  \
      (__attribute__((address_space(3))) unsigned int*)(l), 16, 0, 0)

// ---------------------------------------------------------------------------
// fp32 -> bf16 convert of [support ; query] into one bf16 buffer (fused)
// ---------------------------------------------------------------------------
__global__ void convert_f32_bf16(const float* __restrict__ support,
                                 const float* __restrict__ query,
                                 __bf16* __restrict__ out) {
  const long nsup = (long)N_SUPPORT * D_IN;
  long i = ((long)blockIdx.x * blockDim.x + threadIdx.x) * 4;
  const float* src = (i < nsup) ? (support + i) : (query + (i - nsup));
  float4 v = *(const float4*)src;
  bf16x4 o;
  o[0] = (__bf16)v.x; o[1] = (__bf16)v.y; o[2] = (__bf16)v.z; o[3] = (__bf16)v.w;
  *(bf16x4*)(out + i) = o;
}

// ---------------------------------------------------------------------------
// LDS-tiled transpose: in [rows][cols] f32  ->  out [cols][rows] bf16
// block (32,8), grid (cols/32, rows/32). rows,cols multiples of 32.
// ---------------------------------------------------------------------------
__global__ void transpose_f32_to_bf16(const float* __restrict__ in,
                                      __bf16* __restrict__ out,
                                      int rows, int cols) {
  __shared__ float tile[32][33];
  int bx = blockIdx.x * 32;  // col base
  int by = blockIdx.y * 32;  // row base
  int tx = threadIdx.x;      // 0..31
  int ty = threadIdx.y;      // 0..7
#pragma unroll
  for (int i = ty; i < 32; i += 8)
    tile[i][tx] = in[(long)(by + i) * cols + bx + tx];
  __syncthreads();
#pragma unroll
  for (int i = ty; i < 32; i += 8)
    out[(long)(bx + i) * rows + by + tx] = (__bf16)tile[tx][i];
}

// ---------------------------------------------------------------------------
// bf16 MFMA GEMM:  C[M][N] = A[M][K] @ BT[N][K]^T   (both row-major bf16)
// BM=128, BN template (128 or 64), BK=32. 4 waves in 2x2, 64 x (BN/2) per wave.
// EPI 0: C = bf16, relu(acc + bias[col]); EPI 1: C = f32, acc + bias[col].
// ---------------------------------------------------------------------------
template <int BN, int EPI>
__global__ __launch_bounds__(256, 2) void gemm_bt(
    const __bf16* __restrict__ A, const __bf16* __restrict__ BT,
    const float* __restrict__ bias, void* __restrict__ C,
    int M, int N, int K) {
  constexpr int BM = 128;
  constexpr int BK = 32;
  constexpr int WN = BN / 2;   // wave tile cols
  constexpr int NR = WN / 16;  // n-fragments per wave
  constexpr int MR = 4;        // 64 rows per wave

  __shared__ __align__(16) __bf16 As[BM * BK];
  __shared__ __align__(16) __bf16 Bs[BN * BK];

  const int tid = threadIdx.x;
  const int wave = tid >> 6;
  const int lane = tid & 63;
  const int m0 = blockIdx.x * BM;
  const int n0 = blockIdx.y * BN;
  const int wr = wave >> 1;  // 0..1
  const int wc = wave & 1;   // 0..1
  const int l16 = lane & 15;
  const int half = lane >> 4;  // 0..3

  f32x4 acc[MR][NR];
#pragma unroll
  for (int m = 0; m < MR; ++m)
#pragma unroll
    for (int n = 0; n < NR; ++n) acc[m][n] = (f32x4)0.0f;

  for (int k0 = 0; k0 < K; k0 += BK) {
#pragma unroll
    for (int q = 0; q < BM / 64; ++q) {
      int chunk = q * 256 + tid;        // 16B chunk index
      int row = chunk >> 2;             // BK=32 -> 4 chunks per row
      int kc = chunk & 3;
      GLOAD_LDS16(A + (long)(m0 + row) * K + k0 + kc * 8, As + chunk * 8);
    }
#pragma unroll
    for (int q = 0; q < BN / 64; ++q) {
      int chunk = q * 256 + tid;
      int row = chunk >> 2;
      int kc = chunk & 3;
      GLOAD_LDS16(BT + (long)(n0 + row) * K + k0 + kc * 8, Bs + chunk * 8);
    }
    asm volatile("s_waitcnt vmcnt(0)" ::: "memory");
    __syncthreads();

    bf16x8 a[MR], b[NR];
#pragma unroll
    for (int m = 0; m < MR; ++m)
      a[m] = *(const bf16x8*)(As + (wr * 64 + m * 16 + l16) * BK + half * 8);
#pragma unroll
    for (int n = 0; n < NR; ++n)
      b[n] = *(const bf16x8*)(Bs + (wc * WN + n * 16 + l16) * BK + half * 8);
#pragma unroll
    for (int m = 0; m < MR; ++m)
#pragma unroll
      for (int n = 0; n < NR; ++n)
        acc[m][n] = __builtin_amdgcn_mfma_f32_16x16x32_bf16(a[m], b[n],
                                                            acc[m][n], 0, 0, 0);
    __syncthreads();
  }

  // epilogue: C/D layout col = lane&15, row = (lane>>4)*4 + j  [m89/m91]
#pragma unroll
  for (int m = 0; m < MR; ++m) {
#pragma unroll
    for (int n = 0; n < NR; ++n) {
#pragma unroll
      for (int j = 0; j < 4; ++j) {
        int row = m0 + wr * 64 + m * 16 + half * 4 + j;
        int col = n0 + wc * WN + n * 16 + l16;
        float v = acc[m][n][j] + bias[col];
        if (EPI == 0) {
          v = fmaxf(v, 0.0f);
          ((__bf16*)C)[(long)row * N + col] = (__bf16)v;
        } else {
          ((float*)C)[(long)row * N + col] = v;
        }
      }
    }
  }
}

// ---------------------------------------------------------------------------
// class partial sums, no atomics / no zero-init. grid (64 classes, 8 slices).
// Block (c,s) scans support rows [s*512, (s+1)*512), accumulates rows whose
// label == c, and writes its full 512-col partial slice + local count.
// Label compare is block-uniform -> no divergence.
// ---------------------------------------------------------------------------
__global__ __launch_bounds__(256) void proto_partial(
    const __bf16* __restrict__ s_emb, const int* __restrict__ labels,
    float* __restrict__ sums_part, int* __restrict__ cnt_part) {
  const int c = blockIdx.x;
  const int s = blockIdx.y;  // 0..7
  const int tid = threadIdx.x;
  const int j0 = s * (N_SUPPORT / 8);
  float a0 = 0.0f, a1 = 0.0f;
  int count = 0;
#pragma unroll 4
  for (int j = j0; j < j0 + N_SUPPORT / 8; j += 4) {
    int4 lab4 = *(const int4*)(labels + j);
#pragma unroll
    for (int u = 0; u < 4; ++u) {
      int lab = (u == 0) ? lab4.x : (u == 1) ? lab4.y : (u == 2) ? lab4.z : lab4.w;
      if (lab == c) {
        const __bf16* r = s_emb + (long)(j + u) * D_EMB;
        a0 += (float)r[tid];
        a1 += (float)r[tid + 256];
        ++count;
      }
    }
  }
  float* dst = sums_part + (long)(c * 8 + s) * D_EMB;
  dst[tid] = a0;
  dst[tid + 256] = a1;
  if (tid == 0) cnt_part[c * 8 + s] = count;
}

// ---------------------------------------------------------------------------
// cpb_part[kc][c][n] = sum_{k in chunk kc} means[c][k] * W1[(D_EMB+k)][n]
// grid (64 classes, 4 k-chunks of 128). No atomics, no zero-init.
// b1 is folded into the qp GEMM bias instead.
// ---------------------------------------------------------------------------
__global__ __launch_bounds__(256) void proto_cpb(
    const float* __restrict__ sums_part, const int* __restrict__ cnt_part,
    const float* __restrict__ W1, float* __restrict__ cpb_part) {
  __shared__ float ls[128];
  const int c = blockIdx.x;
  const int kc = blockIdx.y;
  const int k0 = kc * 128;
  const int tid = threadIdx.x;

  int nc = 0;
#pragma unroll
  for (int s = 0; s < 8; ++s) nc += cnt_part[c * 8 + s];
  float inv = 1.0f / fmaxf((float)nc, 1.0f);

  if (tid < 128) {
    float v = 0.0f;
#pragma unroll
    for (int s = 0; s < 8; ++s)
      v += sums_part[(long)(c * 8 + s) * D_EMB + k0 + tid];
    ls[tid] = v * inv;
  }
  __syncthreads();

  float acc = 0.0f;
#pragma unroll 8
  for (int k = 0; k < 128; ++k)
    acc = fmaf(ls[k], W1[(long)(D_EMB + k0 + k) * HIDDEN + tid], acc);
  cpb_part[((long)kc * NUM_CLASSES + c) * HIDDEN + tid] = acc;
}

// ---------------------------------------------------------------------------
// cpb[i] = sum_kc cpb_part[kc][i]   (i over 64*256)
// ---------------------------------------------------------------------------
__global__ void cpb_reduce(const float* __restrict__ cpb_part,
                           float* __restrict__ cpb) {
  int i = blockIdx.x * 256 + threadIdx.x;  // 16384 threads
  const int n = NUM_CLASSES * HIDDEN;
  cpb[i] = cpb_part[i] + cpb_part[n + i] + cpb_part[2 * n + i] +
           cpb_part[3 * n + i];
}

// ---------------------------------------------------------------------------
// fused score: out[q][c] = sigmoid( sum_k relu(qp[q,k]+cpb[c,k]) * W2[k] + b2 )
// qp already includes b1. block = 256 threads = 4 q-rows x 64 classes.
// ---------------------------------------------------------------------------
__global__ __launch_bounds__(256) void score_kernel(
    const float* __restrict__ qp, const float* __restrict__ cpb,
    const float* __restrict__ W2, const float* __restrict__ b2,
    float* __restrict__ out) {
  __shared__ float cpb_s[NUM_CLASSES * (HIDDEN + 1)];
  __shared__ float qp_s[4 * HIDDEN];
  __shared__ float w2_s[HIDDEN];
  int tid = threadIdx.x;
  int q0 = blockIdx.x * 4;

  w2_s[tid] = W2[tid];
  for (int i = tid; i < 4 * HIDDEN; i += 256) qp_s[i] = qp[(long)q0 * HIDDEN + i];
  for (int i = tid; i < NUM_CLASSES * HIDDEN; i += 256)
    cpb_s[(i >> 8) * (HIDDEN + 1) + (i & (HIDDEN - 1))] = cpb[i];
  __syncthreads();

  int qi = tid >> 6;  // wave id -> qp row is wave-uniform (LDS broadcast)
  int c = tid & 63;
  const float* qrow = qp_s + qi * HIDDEN;
  const float* crow = cpb_s + c * (HIDDEN + 1);
  float acc = 0.0f;
#pragma unroll 8
  for (int k = 0; k < HIDDEN; ++k)
    acc = fmaf(fmaxf(qrow[k] + crow[k], 0.0f), w2_s[k], acc);
  float x = acc + b2[0];
  out[(long)(q0 + qi) * NUM_CLASSES + c] = 1.0f / (1.0f + __expf(-x));
}

// ---------------------------------------------------------------------------
extern "C" void kernel_launch(void* const* d_in, const int* in_sizes, int n_in,
                              void* d_out, int out_size, void* d_ws,
                              size_t ws_size, hipStream_t stream) {
  const float* support = (const float*)d_in[0];
  const float* query   = (const float*)d_in[1];
  const int*   labels  = (const int*)d_in[2];
  const float* W_e     = (const float*)d_in[3];
  const float* b_e     = (const float*)d_in[4];
  const float* W1      = (const float*)d_in[5];
  const float* b1      = (const float*)d_in[6];
  const float* W2      = (const float*)d_in[7];
  const float* b2      = (const float*)d_in[8];
  float* out = (float*)d_out;

  char* ws = (char*)d_ws;
  size_t off = 0;
  auto alloc = [&](size_t bytes) {
    void* p = ws + off;
    off = (off + bytes + 255) & ~(size_t)255;
    return p;
  };
  const long NTOT = N_SUPPORT + N_QUERY;  // 12288
  __bf16* Xbf = (__bf16*)alloc((size_t)NTOT * D_IN * 2);            // 25.2 MB
  __bf16* WeT = (__bf16*)alloc((size_t)D_EMB * D_IN * 2);           // 1 MB
  __bf16* WqT = (__bf16*)alloc((size_t)HIDDEN * D_EMB * 2);         // 256 KB
  __bf16* emb = (__bf16*)alloc((size_t)NTOT * D_EMB * 2);           // 12.6 MB
  float*  qp  = (float*)alloc((size_t)N_QUERY * HIDDEN * 4);        // 8.4 MB
  float*  sums_part = (float*)alloc((size_t)NUM_CLASSES * 8 * D_EMB * 4);   // 1 MB
  int*    cnt_part  = (int*)alloc((size_t)NUM_CLASSES * 8 * 4);             // 2 KB
  float*  cpb_part  = (float*)alloc((size_t)4 * NUM_CLASSES * HIDDEN * 4);  // 256 KB
  float*  cpb       = (float*)alloc((size_t)NUM_CLASSES * HIDDEN * 4);      // 64 KB

  // fp32 -> bf16 input conversion ([support; query] concatenated)
  convert_f32_bf16<<<(NTOT * D_IN) / 1024, 256, 0, stream>>>(support, query, Xbf);

  // W_e [1024][512] -> WeT [512][1024] bf16 ; Wq = W1[:512] [512][256] -> WqT [256][512]
  transpose_f32_to_bf16<<<dim3(D_EMB / 32, D_IN / 32), dim3(32, 8), 0, stream>>>(
      W_e, WeT, D_IN, D_EMB);
  transpose_f32_to_bf16<<<dim3(HIDDEN / 32, D_EMB / 32), dim3(32, 8), 0, stream>>>(
      W1, WqT, D_EMB, HIDDEN);

  // embeddings: relu(X @ W_e + b_e) -> bf16 [12288][512]
  gemm_bt<128, 0><<<dim3(NTOT / 128, D_EMB / 128), 256, 0, stream>>>(
      Xbf, WeT, b_e, emb, NTOT, D_EMB, D_IN);

  // class prototypes: partial sums (no atomics) -> projection parts -> reduce
  proto_partial<<<dim3(NUM_CLASSES, 8), 256, 0, stream>>>(emb, labels, sums_part,
                                                          cnt_part);
  proto_cpb<<<dim3(NUM_CLASSES, 4), 256, 0, stream>>>(sums_part, cnt_part, W1,
                                                      cpb_part);
  cpb_reduce<<<NUM_CLASSES * HIDDEN / 256, 256, 0, stream>>>(cpb_part, cpb);

  // qp = q_emb @ Wq + b1  (f32 out [8192][256])
  gemm_bt<64, 1><<<dim3(N_QUERY / 128, HIDDEN / 64), 256, 0, stream>>>(
      emb + (long)N_SUPPORT * D_EMB, WqT, b1, qp, N_QUERY, HIDDEN, D_EMB);

  // fused relation score
  score_kernel<<<N_QUERY / 4, 256, 0, stream>>>(qp, cpb, W2, b2, out);
}

// Round 4
// 100.046 us; speedup vs baseline: 1.4307x; 1.1506x over previous
//
#include <hip/hip_runtime.h>
#include <hip/hip_bf16.h>

// Problem constants
#define D_IN 1024
#define D_EMB 512
#define HIDDEN 256
#define NUM_CLASSES 64
#define N_SUPPORT 4096
#define N_QUERY 8192

typedef __bf16 bf16x8 __attribute__((ext_vector_type(8)));
typedef __bf16 bf16x4 __attribute__((ext_vector_type(4)));
typedef float f32x4 __attribute__((ext_vector_type(4)));

#define GLOAD_LDS16(g, l)                                                          \
  __builtin_amdgcn_global_load_lds(                                                \
      (const __attribute__((address_space(1))) unsigned int*)(g),                  \
      (__attribute__((address_space(3))) unsigned int*)(l), 16, 0, 0)

// ---------------------------------------------------------------------------
// Fused transpose of both weight matrices -> bf16 [cols][rows]:
//   blocks [0,512):  W_e [1024][512]  -> WeT [512][1024]
//   blocks [512,640): W1[:512][256]   -> WqT [256][512]
// block (32,8)
// ---------------------------------------------------------------------------
__global__ void transpose_weights(const float* __restrict__ W_e,
                                  const float* __restrict__ W1,
                                  __bf16* __restrict__ WeT,
                                  __bf16* __restrict__ WqT) {
  __shared__ float tile[32][33];
  const float* in;
  __bf16* out;
  int bx, by, rows, cols;
  int b = blockIdx.x;
  if (b < 512) {
    in = W_e; out = WeT; rows = D_IN; cols = D_EMB;
    bx = (b & 15) * 32; by = (b >> 4) * 32;
  } else {
    b -= 512;
    in = W1; out = WqT; rows = D_EMB; cols = HIDDEN;  // W1[:512] only
    bx = (b & 7) * 32; by = (b >> 3) * 32;
  }
  int tx = threadIdx.x;  // 0..31
  int ty = threadIdx.y;  // 0..7
#pragma unroll
  for (int i = ty; i < 32; i += 8)
    tile[i][tx] = in[(long)(by + i) * cols + bx + tx];
  __syncthreads();
#pragma unroll
  for (int i = ty; i < 32; i += 8)
    out[(long)(bx + i) * rows + by + tx] = (__bf16)tile[tx][i];
}

// ---------------------------------------------------------------------------
// Embedding GEMM with fused fp32->bf16 A conversion:
//   emb[M][512] = relu( [support;query](fp32) @ WeT^T + b_e )  -> bf16
// BM=128, BN=128, BK=32. A reg-staged from fp32 (cvt in-kernel, padded LDS);
// B staged via global_load_lds (linear LDS).
// ---------------------------------------------------------------------------
__global__ __launch_bounds__(256, 2) void gemm_emb(
    const float* __restrict__ support, const float* __restrict__ query,
    const __bf16* __restrict__ BT, const float* __restrict__ bias,
    __bf16* __restrict__ C) {
  constexpr int BM = 128, BN = 128, BK = 32;
  constexpr int N = D_EMB, K = D_IN;
  constexpr int LDA_S = 40;  // padded bf16 stride for As (16B-aligned rows)
  constexpr int WN = BN / 2, NR = WN / 16, MR = 4;

  __shared__ __align__(16) __bf16 As[BM * LDA_S];
  __shared__ __align__(16) __bf16 Bs[BN * BK];

  const int tid = threadIdx.x;
  const int wave = tid >> 6;
  const int lane = tid & 63;
  const int m0 = blockIdx.x * BM;
  const int n0 = blockIdx.y * BN;
  const int wr = wave >> 1;
  const int wc = wave & 1;
  const int l16 = lane & 15;
  const int half = lane >> 4;

  // block never straddles the support/query boundary (4096 % 128 == 0)
  const float* Abase =
      (m0 < N_SUPPORT) ? (support + (long)m0 * K) : (query + (long)(m0 - N_SUPPORT) * K);

  f32x4 acc[MR][NR];
#pragma unroll
  for (int m = 0; m < MR; ++m)
#pragma unroll
    for (int n = 0; n < NR; ++n) acc[m][n] = (f32x4)0.0f;

  for (int k0 = 0; k0 < K; k0 += BK) {
    // A: 128x32 fp32 tile -> 4 float4 loads per thread
    float4 av[4];
#pragma unroll
    for (int q = 0; q < 4; ++q) {
      int idx = q * 256 + tid;          // float4 index within tile
      int row = idx >> 3;               // 8 float4 per row
      int c4 = idx & 7;
      av[q] = *(const float4*)(Abase + (long)row * K + k0 + c4 * 4);
    }
    // B: 128x32 bf16 tile via global_load_lds
#pragma unroll
    for (int q = 0; q < 2; ++q) {
      int chunk = q * 256 + tid;
      int row = chunk >> 2;
      int kc = chunk & 3;
      GLOAD_LDS16(BT + (long)(n0 + row) * K + k0 + kc * 8, Bs + chunk * 8);
    }
    // convert A and write to padded LDS
#pragma unroll
    for (int q = 0; q < 4; ++q) {
      int idx = q * 256 + tid;
      int row = idx >> 3;
      int c4 = idx & 7;
      bf16x4 o;
      o[0] = (__bf16)av[q].x; o[1] = (__bf16)av[q].y;
      o[2] = (__bf16)av[q].z; o[3] = (__bf16)av[q].w;
      *(bf16x4*)(As + row * LDA_S + c4 * 4) = o;
    }
    asm volatile("s_waitcnt vmcnt(0)" ::: "memory");
    __syncthreads();

    bf16x8 a[MR], b[NR];
#pragma unroll
    for (int m = 0; m < MR; ++m)
      a[m] = *(const bf16x8*)(As + (wr * 64 + m * 16 + l16) * LDA_S + half * 8);
#pragma unroll
    for (int n = 0; n < NR; ++n)
      b[n] = *(const bf16x8*)(Bs + (wc * WN + n * 16 + l16) * BK + half * 8);
#pragma unroll
    for (int m = 0; m < MR; ++m)
#pragma unroll
      for (int n = 0; n < NR; ++n)
        acc[m][n] = __builtin_amdgcn_mfma_f32_16x16x32_bf16(a[m], b[n],
                                                            acc[m][n], 0, 0, 0);
    __syncthreads();
  }

  // epilogue: C/D layout col = lane&15, row = (lane>>4)*4 + j
#pragma unroll
  for (int m = 0; m < MR; ++m)
#pragma unroll
    for (int n = 0; n < NR; ++n)
#pragma unroll
      for (int j = 0; j < 4; ++j) {
        int row = m0 + wr * 64 + m * 16 + half * 4 + j;
        int col = n0 + wc * WN + n * 16 + l16;
        float v = fmaxf(acc[m][n][j] + bias[col], 0.0f);
        C[(long)row * N + col] = (__bf16)v;
      }
}

// ---------------------------------------------------------------------------
// bf16 MFMA GEMM (bf16 A):  C[M][N] = A @ BT^T + bias, f32 out (for qp)
// BM=128, BN=64. Same structure as gemm_emb but A via global_load_lds.
// ---------------------------------------------------------------------------
__global__ __launch_bounds__(256, 2) void gemm_qp(
    const __bf16* __restrict__ A, const __bf16* __restrict__ BT,
    const float* __restrict__ bias, float* __restrict__ C, int M, int N, int K) {
  constexpr int BM = 128, BN = 64, BK = 32;
  constexpr int WN = BN / 2, NR = WN / 16, MR = 4;

  __shared__ __align__(16) __bf16 As[BM * BK];
  __shared__ __align__(16) __bf16 Bs[BN * BK];

  const int tid = threadIdx.x;
  const int wave = tid >> 6;
  const int lane = tid & 63;
  const int m0 = blockIdx.x * BM;
  const int n0 = blockIdx.y * BN;
  const int wr = wave >> 1;
  const int wc = wave & 1;
  const int l16 = lane & 15;
  const int half = lane >> 4;

  f32x4 acc[MR][NR];
#pragma unroll
  for (int m = 0; m < MR; ++m)
#pragma unroll
    for (int n = 0; n < NR; ++n) acc[m][n] = (f32x4)0.0f;

  for (int k0 = 0; k0 < K; k0 += BK) {
#pragma unroll
    for (int q = 0; q < BM / 64; ++q) {
      int chunk = q * 256 + tid;
      int row = chunk >> 2;
      int kc = chunk & 3;
      GLOAD_LDS16(A + (long)(m0 + row) * K + k0 + kc * 8, As + chunk * 8);
    }
    {
      int chunk = tid;  // BN=64: 256 chunks
      int row = chunk >> 2;
      int kc = chunk & 3;
      GLOAD_LDS16(BT + (long)(n0 + row) * K + k0 + kc * 8, Bs + chunk * 8);
    }
    asm volatile("s_waitcnt vmcnt(0)" ::: "memory");
    __syncthreads();

    bf16x8 a[MR], b[NR];
#pragma unroll
    for (int m = 0; m < MR; ++m)
      a[m] = *(const bf16x8*)(As + (wr * 64 + m * 16 + l16) * BK + half * 8);
#pragma unroll
    for (int n = 0; n < NR; ++n)
      b[n] = *(const bf16x8*)(Bs + (wc * WN + n * 16 + l16) * BK + half * 8);
#pragma unroll
    for (int m = 0; m < MR; ++m)
#pragma unroll
      for (int n = 0; n < NR; ++n)
        acc[m][n] = __builtin_amdgcn_mfma_f32_16x16x32_bf16(a[m], b[n],
                                                            acc[m][n], 0, 0, 0);
    __syncthreads();
  }

#pragma unroll
  for (int m = 0; m < MR; ++m)
#pragma unroll
    for (int n = 0; n < NR; ++n)
#pragma unroll
      for (int j = 0; j < 4; ++j) {
        int row = m0 + wr * 64 + m * 16 + half * 4 + j;
        int col = n0 + wc * WN + n * 16 + l16;
        C[(long)row * N + col] = acc[m][n][j] + bias[col];
      }
}

// ---------------------------------------------------------------------------
// class partial sums, no atomics / no zero-init. grid (64 classes, 8 slices).
// ---------------------------------------------------------------------------
__global__ __launch_bounds__(256) void proto_partial(
    const __bf16* __restrict__ s_emb, const int* __restrict__ labels,
    float* __restrict__ sums_part, int* __restrict__ cnt_part) {
  const int c = blockIdx.x;
  const int s = blockIdx.y;  // 0..7
  const int tid = threadIdx.x;
  const int j0 = s * (N_SUPPORT / 8);
  float a0 = 0.0f, a1 = 0.0f;
  int count = 0;
#pragma unroll 4
  for (int j = j0; j < j0 + N_SUPPORT / 8; j += 4) {
    int4 lab4 = *(const int4*)(labels + j);
#pragma unroll
    for (int u = 0; u < 4; ++u) {
      int lab = (u == 0) ? lab4.x : (u == 1) ? lab4.y : (u == 2) ? lab4.z : lab4.w;
      if (lab == c) {
        const __bf16* r = s_emb + (long)(j + u) * D_EMB;
        a0 += (float)r[tid];
        a1 += (float)r[tid + 256];
        ++count;
      }
    }
  }
  float* dst = sums_part + (long)(c * 8 + s) * D_EMB;
  dst[tid] = a0;
  dst[tid + 256] = a1;
  if (tid == 0) cnt_part[c * 8 + s] = count;
}

// ---------------------------------------------------------------------------
// cpb_part[kc][c][n] = sum_{k in chunk kc} means[c][k] * W1[(D_EMB+k)][n]
// grid (64, 4). b1 folded into qp GEMM bias.
// ---------------------------------------------------------------------------
__global__ __launch_bounds__(256) void proto_cpb(
    const float* __restrict__ sums_part, const int* __restrict__ cnt_part,
    const float* __restrict__ W1, float* __restrict__ cpb_part) {
  __shared__ float ls[128];
  const int c = blockIdx.x;
  const int kc = blockIdx.y;
  const int k0 = kc * 128;
  const int tid = threadIdx.x;

  int nc = 0;
#pragma unroll
  for (int s = 0; s < 8; ++s) nc += cnt_part[c * 8 + s];
  float inv = 1.0f / fmaxf((float)nc, 1.0f);

  if (tid < 128) {
    float v = 0.0f;
#pragma unroll
    for (int s = 0; s < 8; ++s)
      v += sums_part[(long)(c * 8 + s) * D_EMB + k0 + tid];
    ls[tid] = v * inv;
  }
  __syncthreads();

  float acc = 0.0f;
#pragma unroll 8
  for (int k = 0; k < 128; ++k)
    acc = fmaf(ls[k], W1[(long)(D_EMB + k0 + k) * HIDDEN + tid], acc);
  cpb_part[((long)kc * NUM_CLASSES + c) * HIDDEN + tid] = acc;
}

__global__ void cpb_reduce(const float* __restrict__ cpb_part,
                           float* __restrict__ cpb) {
  int i = blockIdx.x * 256 + threadIdx.x;  // 16384 threads
  const int n = NUM_CLASSES * HIDDEN;
  cpb[i] = cpb_part[i] + cpb_part[n + i] + cpb_part[2 * n + i] +
           cpb_part[3 * n + i];
}

// ---------------------------------------------------------------------------
// fused score: out[q][c] = sigmoid( sum_k relu(qp[q,k]+cpb[c,k]) * W2[k] + b2 )
// lane = class c; wave handles 8 q-rows; block = 4 waves = 32 q-rows.
// grid = 256 blocks. cpb (stride 260), qp, w2 staged in LDS once per block.
// Per k-chunk: 1 per-lane ds_read_b128 (cpb) + uniform reads + 12 VALU x 8q.
// ---------------------------------------------------------------------------
__global__ __launch_bounds__(256) void score_kernel(
    const float* __restrict__ qp, const float* __restrict__ cpb,
    const float* __restrict__ W2, const float* __restrict__ b2,
    float* __restrict__ out) {
  constexpr int CPB_S = 260;  // f32 stride: 1040 B, 16B aligned, conflict-free
  __shared__ __align__(16) float cpb_s[NUM_CLASSES * CPB_S];  // 66.6 KB
  __shared__ __align__(16) float qp_s[32 * HIDDEN];           // 32 KB
  __shared__ __align__(16) float w2_s[HIDDEN];                // 1 KB

  const int tid = threadIdx.x;
  const int w = tid >> 6;    // wave 0..3
  const int c = tid & 63;    // class = lane
  const int qb0 = blockIdx.x * 32;

  w2_s[tid] = W2[tid];
  for (int i = tid; i < NUM_CLASSES * HIDDEN; i += 256)
    cpb_s[(i >> 8) * CPB_S + (i & (HIDDEN - 1))] = cpb[i];
  for (int i = tid; i < 32 * HIDDEN; i += 256)
    qp_s[i] = qp[(long)qb0 * HIDDEN + i];
  __syncthreads();

  const float bb = b2[0];
  float acc[8];
#pragma unroll
  for (int q = 0; q < 8; ++q) acc[q] = 0.0f;

  const float* crow = cpb_s + c * CPB_S;
  const float* qbase = qp_s + (w * 8) * HIDDEN;

#pragma unroll 4
  for (int kc = 0; kc < HIDDEN / 4; ++kc) {
    f32x4 cv = *(const f32x4*)(crow + kc * 4);
    f32x4 wv = *(const f32x4*)(w2_s + kc * 4);
#pragma unroll
    for (int q = 0; q < 8; ++q) {
      f32x4 qv = *(const f32x4*)(qbase + q * HIDDEN + kc * 4);
      acc[q] = fmaf(fmaxf(qv[0] + cv[0], 0.0f), wv[0], acc[q]);
      acc[q] = fmaf(fmaxf(qv[1] + cv[1], 0.0f), wv[1], acc[q]);
      acc[q] = fmaf(fmaxf(qv[2] + cv[2], 0.0f), wv[2], acc[q]);
      acc[q] = fmaf(fmaxf(qv[3] + cv[3], 0.0f), wv[3], acc[q]);
    }
  }

#pragma unroll
  for (int q = 0; q < 8; ++q) {
    float x = acc[q] + bb;
    out[(long)(qb0 + w * 8 + q) * NUM_CLASSES + c] = 1.0f / (1.0f + __expf(-x));
  }
}

// ---------------------------------------------------------------------------
extern "C" void kernel_launch(void* const* d_in, const int* in_sizes, int n_in,
                              void* d_out, int out_size, void* d_ws,
                              size_t ws_size, hipStream_t stream) {
  const float* support = (const float*)d_in[0];
  const float* query   = (const float*)d_in[1];
  const int*   labels  = (const int*)d_in[2];
  const float* W_e     = (const float*)d_in[3];
  const float* b_e     = (const float*)d_in[4];
  const float* W1      = (const float*)d_in[5];
  const float* b1      = (const float*)d_in[6];
  const float* W2      = (const float*)d_in[7];
  const float* b2      = (const float*)d_in[8];
  float* out = (float*)d_out;

  char* ws = (char*)d_ws;
  size_t off = 0;
  auto alloc = [&](size_t bytes) {
    void* p = ws + off;
    off = (off + bytes + 255) & ~(size_t)255;
    return p;
  };
  const long NTOT = N_SUPPORT + N_QUERY;  // 12288
  __bf16* WeT = (__bf16*)alloc((size_t)D_EMB * D_IN * 2);           // 1 MB
  __bf16* WqT = (__bf16*)alloc((size_t)HIDDEN * D_EMB * 2);         // 256 KB
  __bf16* emb = (__bf16*)alloc((size_t)NTOT * D_EMB * 2);           // 12.6 MB
  float*  qp  = (float*)alloc((size_t)N_QUERY * HIDDEN * 4);        // 8.4 MB
  float*  sums_part = (float*)alloc((size_t)NUM_CLASSES * 8 * D_EMB * 4);   // 1 MB
  int*    cnt_part  = (int*)alloc((size_t)NUM_CLASSES * 8 * 4);             // 2 KB
  float*  cpb_part  = (float*)alloc((size_t)4 * NUM_CLASSES * HIDDEN * 4);  // 256 KB
  float*  cpb       = (float*)alloc((size_t)NUM_CLASSES * HIDDEN * 4);      // 64 KB

  // both weight transposes in one dispatch
  transpose_weights<<<640, dim3(32, 8), 0, stream>>>(W_e, W1, WeT, WqT);

  // embeddings with fused fp32->bf16 A conversion: relu(X @ W_e + b_e) -> bf16
  gemm_emb<<<dim3(NTOT / 128, D_EMB / 128), 256, 0, stream>>>(
      support, query, WeT, b_e, emb);

  // class prototypes: partial sums (no atomics) -> projection parts -> reduce
  proto_partial<<<dim3(NUM_CLASSES, 8), 256, 0, stream>>>(emb, labels, sums_part,
                                                          cnt_part);
  proto_cpb<<<dim3(NUM_CLASSES, 4), 256, 0, stream>>>(sums_part, cnt_part, W1,
                                                      cpb_part);
  cpb_reduce<<<NUM_CLASSES * HIDDEN / 256, 256, 0, stream>>>(cpb_part, cpb);

  // qp = q_emb @ Wq + b1  (f32 out [8192][256])
  gemm_qp<<<dim3(N_QUERY / 128, HIDDEN / 64), 256, 0, stream>>>(
      emb + (long)N_SUPPORT * D_EMB, WqT, b1, qp, N_QUERY, HIDDEN, D_EMB);

  // fused relation score
  score_kernel<<<N_QUERY / 32, 256, 0, stream>>>(qp, cpb, W2, b2, out);
}